// Round 12
// baseline (305.762 us; speedup 1.0000x reference)
//
#include <hip/hip_runtime.h>

#define LTC_B 512
#define LTC_H 512
#define LTC_I 256

static constexpr float kL2E = 1.4426950408889634f;  // log2(e)

// f32 weight quad per (j,h): a = -sigma*log2(e), ec = 2^(mu*sigma*log2(e)),
// wz = W*erev, wd = W.  sigma(b,j,h) = 1 / (1 + ec * 2^(a*v(b,j))).
// Quad index = (ht4*K + j)*4 + hh4, h = ht4*4 + hh4: the 4 h's of one (ht4,j)
// are one contiguous 64B group -> batched s_load_dwordx16 on the scalar pipe.
template<int K, int LOG2K>
__global__ void ltc_prep(const float* __restrict__ mu, const float* __restrict__ sigma,
                         const float* __restrict__ W, const float* __restrict__ erev,
                         float4* __restrict__ slab) {
    const int t = blockIdx.x * 256 + threadIdx.x;   // one thread per quad
    if (t >= K * LTC_H) return;
    const int hh4  = t & 3;
    const int rest = t >> 2;
    const int j    = rest & (K - 1);
    const int ht4  = rest >> LOG2K;
    const int h    = ht4 * 4 + hh4;
    const int g    = j * LTC_H + h;
    const float sg = sigma[g];
    float4 o;
    o.x = -sg * kL2E;                    // a
    o.y = exp2f(mu[g] * sg * kL2E);      // ec = 2^c
    o.z = W[g] * erev[g];                // wz
    o.w = W[g];                          // wd
    slab[t] = o;                         // coalesced 16B/lane
}

// 64x64 LDS tile transpose: in R x C row-major -> out C x R. grid (C/64, R/64).
__global__ void ltc_transpose(const float* __restrict__ in, float* __restrict__ out,
                              int R, int C) {
    __shared__ float tile[64][65];
    const int bx = blockIdx.x * 64;      // col base
    const int by = blockIdx.y * 64;      // row base
    const int tx = threadIdx.x & 63;
    const int t4 = threadIdx.x >> 6;
    #pragma unroll
    for (int r = t4; r < 64; r += 4)
        tile[r][tx] = in[(size_t)(by + r) * C + bx + tx];
    __syncthreads();
    #pragma unroll
    for (int r = t4; r < 64; r += 4)
        out[(size_t)(bx + r) * R + by + tx] = tile[tx][r];
}

// Lane = BATCH, scalar-SGPR weights -- R4 (291.5us) structure byte-for-byte
// EXCEPT one isolated change: 4-way rcp batching (1 rcp / 4 sigmoids instead
// of 1 / 2). Trans ops per eval drop 1.5 -> 1.25 at the cost of +3 full-rate
// muls per 4 evals; the kernel is issue-bound so this trades 16-cyc trans
// issue for 6 cyc of VALU. Numerics proven in R8 (absmax 4.9e-4 << 7.3e-3).
// Block = 512 thr = 8 waves = 8 j-slices for one (4-h tile, 64-b column).
// MODE: 0 = sensory (write snumT/sdenT HxB), 1 = recurrent (write vT KxB),
//       2 = last recurrent (write out B x H).
template<int K, int MODE>
__global__ __launch_bounds__(512, 8)
void ltc_pass(const float* __restrict__ vT,      // K x B (transposed)
              const float4* __restrict__ slab,   // [128][K][4]
              const float* __restrict__ snumT, const float* __restrict__ sdenT, // H x B
              const float* __restrict__ vleak, const float* __restrict__ gleak,
              const float* __restrict__ cm,
              float* __restrict__ o0, float* __restrict__ o1)
{
    constexpr int JW = K / 8;                    // j's per wave (64 / 32)

    __shared__ float2 comb[8][4][64];            // 16 KB partials

    const int tid  = threadIdx.x;
    const int lane = tid & 63;
    const int wu   = __builtin_amdgcn_readfirstlane(tid >> 6);  // j-slice
    const int ht4  = blockIdx.x;                 // 0..127
    const int b0   = blockIdx.y * 64;

    // wave's weight slice (wave-uniform float4 -> batched s_load)
    const float4* __restrict__ wq = slab + ((size_t)ht4 * K + (size_t)wu * JW) * 4;
    // per-lane v: coalesced 4B loads, one per j
    const float* __restrict__ vp = vT + (size_t)(wu * JW) * LTC_B + b0 + lane;

    float na0 = 0.f, da0 = 0.f, na1 = 0.f, da1 = 0.f;
    float na2 = 0.f, da2 = 0.f, na3 = 0.f, da3 = 0.f;

    #pragma unroll 4
    for (int jj = 0; jj < JW; ++jj) {
        const float vj = vp[(size_t)jj * LTC_B];
        const float4 q0 = wq[jj * 4 + 0];        // wave-uniform -> s_load
        const float4 q1 = wq[jj * 4 + 1];
        const float4 q2 = wq[jj * 4 + 2];
        const float4 q3 = wq[jj * 4 + 3];
        const float e0 = __builtin_amdgcn_exp2f(q0.x * vj);
        const float e1 = __builtin_amdgcn_exp2f(q1.x * vj);
        const float e2 = __builtin_amdgcn_exp2f(q2.x * vj);
        const float e3 = __builtin_amdgcn_exp2f(q3.x * vj);
        const float d0 = fmaf(q0.y, e0, 1.0f);
        const float d1 = fmaf(q1.y, e1, 1.0f);
        const float d2 = fmaf(q2.y, e2, 1.0f);
        const float d3 = fmaf(q3.y, e3, 1.0f);
        const float p01 = d0 * d1, p23 = d2 * d3;
        const float r = __builtin_amdgcn_rcpf(p01 * p23);   // 1 rcp / 4 sigmoids
        const float rp23 = r * p23, rp01 = r * p01;
        const float s0 = rp23 * d1, s1 = rp23 * d0;
        const float s2 = rp01 * d3, s3 = rp01 * d2;
        na0 = fmaf(q0.z, s0, na0); da0 = fmaf(q0.w, s0, da0);
        na1 = fmaf(q1.z, s1, na1); da1 = fmaf(q1.w, s1, da1);
        na2 = fmaf(q2.z, s2, na2); da2 = fmaf(q2.w, s2, da2);
        na3 = fmaf(q3.z, s3, na3); da3 = fmaf(q3.w, s3, da3);
    }

    comb[wu][0][lane] = make_float2(na0, da0);
    comb[wu][1][lane] = make_float2(na1, da1);
    comb[wu][2][lane] = make_float2(na2, da2);
    comb[wu][3][lane] = make_float2(na3, da3);
    __syncthreads();

    if (wu < 4) {                                // wave wu finishes h = ht4*4+wu
        float na = 0.f, da = 0.f;
        #pragma unroll
        for (int js = 0; js < 8; ++js) {
            const float2 p = comb[js][wu][lane];
            na += p.x; da += p.y;
        }
        const int h = ht4 * 4 + wu;
        const int b = b0 + lane;
        const size_t hb = (size_t)h * LTC_B + b;
        if constexpr (MODE == 0) {
            o0[hb] = na;                         // snumT (coalesced)
            o1[hb] = da;                         // sdenT
        } else {
            const float gl = gleak[h], vl = vleak[h], c0 = cm[h];
            const float vpre = vT[hb];           // K==H here, coalesced
            const float num = fmaf(c0, vpre, gl * vl) + na + snumT[hb];
            const float den = c0 + gl + da + sdenT[hb];
            const float vn = num * __builtin_amdgcn_rcpf(den + 1e-8f);
            if constexpr (MODE == 1) o0[hb] = vn;            // next vT (KxB)
            else o0[(size_t)b * LTC_H + h] = vn;             // final B x H
        }
    }
}

extern "C" void kernel_launch(void* const* d_in, const int* in_sizes, int n_in,
                              void* d_out, int out_size, void* d_ws, size_t ws_size,
                              hipStream_t stream) {
    const float* inputs = (const float*)d_in[0];   // B x I
    const float* state  = (const float*)d_in[1];   // B x H
    const float* smu    = (const float*)d_in[2];   // I x H
    const float* ssig   = (const float*)d_in[3];
    const float* sW     = (const float*)d_in[4];
    const float* serev  = (const float*)d_in[5];
    const float* mu     = (const float*)d_in[6];   // H x H
    const float* sig    = (const float*)d_in[7];
    const float* W      = (const float*)d_in[8];
    const float* erev   = (const float*)d_in[9];
    const float* vleak  = (const float*)d_in[10];  // H
    const float* gleak  = (const float*)d_in[11];
    const float* cm     = (const float*)d_in[12];

    float* out = (float*)d_out;                    // B x H
    char*  ws  = (char*)d_ws;
    float*  snumT = (float*)(ws);                            // 1MB  H x B
    float*  sdenT = (float*)(ws + 1 * 1048576);              // 1MB  H x B
    float*  vTA   = (float*)(ws + 2 * 1048576);              // 1MB  H x B
    float*  vTB   = (float*)(ws + 3 * 1048576);              // 1MB  H x B
    float4* rslab = (float4*)(ws + 4 * 1048576);             // 4MB  [128][512][4]
    float4* sslab = (float4*)(ws + 8 * 1048576);             // 2MB  [128][256][4]
    float*  inpT  = (float*)(ws + 10 * 1048576);             // 0.5MB I x B

    // Weight transform (f32 quads, once per launch). One thread per (j,h).
    ltc_prep<LTC_H, 9><<<LTC_H * LTC_H / 256, 256, 0, stream>>>(mu, sig, W, erev, rslab);
    ltc_prep<LTC_I, 8><<<LTC_I * LTC_H / 256, 256, 0, stream>>>(smu, ssig, sW, serev, sslab);

    // Transpose activations into K x B layout.
    ltc_transpose<<<dim3(LTC_I / 64, LTC_B / 64), 256, 0, stream>>>(inputs, inpT, LTC_B, LTC_I);
    ltc_transpose<<<dim3(LTC_H / 64, LTC_B / 64), 256, 0, stream>>>(state, vTA, LTC_B, LTC_H);

    dim3 grid(LTC_H / 4, LTC_B / 64);              // (128 h-tiles, 8 b-cols)
    dim3 blk(512);

    // Sensory pass -> snumT/sdenT (H x B).
    ltc_pass<LTC_I, 0><<<grid, blk, 0, stream>>>(
        inpT, sslab, nullptr, nullptr, nullptr, nullptr, nullptr,
        snumT, sdenT);

    // 6 unfolds: vTA -> vTB -> ... ; last writes B x H into d_out.
    const float* vin = vTA;
    float* vping[5] = {vTB, vTA, vTB, vTA, vTB};
    for (int s = 0; s < 5; ++s) {
        ltc_pass<LTC_H, 1><<<grid, blk, 0, stream>>>(
            vin, rslab, snumT, sdenT, vleak, gleak, cm,
            vping[s], nullptr);
        vin = vping[s];
    }
    ltc_pass<LTC_H, 2><<<grid, blk, 0, stream>>>(
        vin, rslab, snumT, sdenT, vleak, gleak, cm, out, nullptr);
}

// Round 13
// 291.087 us; speedup vs baseline: 1.0504x; 1.0504x over previous
//
#include <hip/hip_runtime.h>

#define LTC_B 512
#define LTC_H 512
#define LTC_I 256

typedef float v2f __attribute__((ext_vector_type(2)));
static constexpr float kL2E = 1.4426950408889634f;  // log2(e)

__device__ __forceinline__ v2f sp(float s) { return (v2f){s, s}; }
__device__ __forceinline__ v2f vexp2(v2f t) {
    return (v2f){__builtin_amdgcn_exp2f(t.x), __builtin_amdgcn_exp2f(t.y)};
}
__device__ __forceinline__ v2f vrcp(v2f t) {
    return (v2f){__builtin_amdgcn_rcpf(t.x), __builtin_amdgcn_rcpf(t.y)};
}

// f32 weight quad per (j,h): a = -sigma*log2(e), ec = 2^(mu*sigma*log2(e)),
// wz = W*erev, wd = W.  sigma(b,j,h) = 1 / (1 + ec * 2^(a*v(b,j))).
// Quad index = (ht4*K + j)*4 + hh4, h = ht4*4 + hh4: the 4 h's of one (ht4,j)
// are one contiguous 64B group -> batched s_load on the scalar pipe.
template<int K, int LOG2K>
__global__ void ltc_prep(const float* __restrict__ mu, const float* __restrict__ sigma,
                         const float* __restrict__ W, const float* __restrict__ erev,
                         float4* __restrict__ slab) {
    const int t = blockIdx.x * 256 + threadIdx.x;   // one thread per quad
    if (t >= K * LTC_H) return;
    const int hh4  = t & 3;
    const int rest = t >> 2;
    const int j    = rest & (K - 1);
    const int ht4  = rest >> LOG2K;
    const int h    = ht4 * 4 + hh4;
    const int g    = j * LTC_H + h;
    const float sg = sigma[g];
    float4 o;
    o.x = -sg * kL2E;                    // a
    o.y = exp2f(mu[g] * sg * kL2E);      // ec = 2^c
    o.z = W[g] * erev[g];                // wz
    o.w = W[g];                          // wd
    slab[t] = o;                         // coalesced 16B/lane
}

// 64x64 LDS tile transpose: in R x C row-major -> out C x R. grid (C/64, R/64).
__global__ void ltc_transpose(const float* __restrict__ in, float* __restrict__ out,
                              int R, int C) {
    __shared__ float tile[64][65];
    const int bx = blockIdx.x * 64;      // col base
    const int by = blockIdx.y * 64;      // row base
    const int tx = threadIdx.x & 63;
    const int t4 = threadIdx.x >> 6;
    #pragma unroll
    for (int r = t4; r < 64; r += 4)
        tile[r][tx] = in[(size_t)(by + r) * C + bx + tx];
    __syncthreads();
    #pragma unroll
    for (int r = t4; r < 64; r += 4)
        out[(size_t)(bx + r) * R + by + tx] = tile[tx][r];
}

// Lane = BATCH-PAIR: R4 (291.5us) skeleton with one isolated change -- each
// lane processes TWO batch elements (b0+2*lane, b0+2*lane+1) as v2f streams.
// Mechanism: 2x independent dependency chains per lane (covers exp2/rcp
// latency that R12 showed on the critical path) + the wave-uniform s_load
// weight stream amortizes over 2x evals. v loads become coalesced dwordx2.
// Weights stay float4 s_loads (R9's v2f weight loads regressed). 2-way rcp
// (proven best). Block = 512 thr = 8 waves = 8 j-slices for one (4-h tile,
// 128-b column). Grid (128, 4) = 512 blocks.
// MODE: 0 = sensory (write snumT/sdenT HxB), 1 = recurrent (write vT KxB),
//       2 = last recurrent (write out B x H).
template<int K, int MODE>
__global__ __launch_bounds__(512, 8)
void ltc_pass(const float* __restrict__ vT,      // K x B (transposed)
              const float4* __restrict__ slab,   // [128][K][4]
              const float* __restrict__ snumT, const float* __restrict__ sdenT, // H x B
              const float* __restrict__ vleak, const float* __restrict__ gleak,
              const float* __restrict__ cm,
              float* __restrict__ o0, float* __restrict__ o1)
{
    constexpr int JW = K / 8;                    // j's per wave (64 / 32)

    __shared__ v2f combN[8][4][64];              // 16 KB na partials (b-pair)
    __shared__ v2f combD[8][4][64];              // 16 KB da partials

    const int tid  = threadIdx.x;
    const int lane = tid & 63;
    const int wu   = __builtin_amdgcn_readfirstlane(tid >> 6);  // j-slice
    const int ht4  = blockIdx.x;                 // 0..127
    const int b0   = blockIdx.y * 128;           // 128 b per block

    // wave's weight slice (wave-uniform float4 -> batched s_load)
    const float4* __restrict__ wq = slab + ((size_t)ht4 * K + (size_t)wu * JW) * 4;
    // per-lane v: coalesced 8B loads (b-pair), one per j
    const v2f* __restrict__ vp =
        (const v2f*)vT + (size_t)(wu * JW) * (LTC_B / 2) + (b0 >> 1) + lane;

    v2f na0 = sp(0.f), da0 = sp(0.f), na1 = sp(0.f), da1 = sp(0.f);
    v2f na2 = sp(0.f), da2 = sp(0.f), na3 = sp(0.f), da3 = sp(0.f);

    #pragma unroll 4
    for (int jj = 0; jj < JW; ++jj) {
        const v2f vj = vp[(size_t)jj * (LTC_B / 2)];
        const float4 q0 = wq[jj * 4 + 0];        // wave-uniform -> s_load
        const float4 q1 = wq[jj * 4 + 1];
        const float4 q2 = wq[jj * 4 + 2];
        const float4 q3 = wq[jj * 4 + 3];
        const v2f e0 = vexp2(sp(q0.x) * vj);
        const v2f e1 = vexp2(sp(q1.x) * vj);
        const v2f e2 = vexp2(sp(q2.x) * vj);
        const v2f e3 = vexp2(sp(q3.x) * vj);
        const v2f d0 = __builtin_elementwise_fma(sp(q0.y), e0, sp(1.0f));
        const v2f d1 = __builtin_elementwise_fma(sp(q1.y), e1, sp(1.0f));
        const v2f d2 = __builtin_elementwise_fma(sp(q2.y), e2, sp(1.0f));
        const v2f d3 = __builtin_elementwise_fma(sp(q3.y), e3, sp(1.0f));
        const v2f r01 = vrcp(d0 * d1);           // 1 rcp / 2 sigmoids (per b)
        const v2f r23 = vrcp(d2 * d3);
        const v2f s0 = r01 * d1, s1 = r01 * d0;
        const v2f s2 = r23 * d3, s3 = r23 * d2;
        na0 = __builtin_elementwise_fma(sp(q0.z), s0, na0);
        da0 = __builtin_elementwise_fma(sp(q0.w), s0, da0);
        na1 = __builtin_elementwise_fma(sp(q1.z), s1, na1);
        da1 = __builtin_elementwise_fma(sp(q1.w), s1, da1);
        na2 = __builtin_elementwise_fma(sp(q2.z), s2, na2);
        da2 = __builtin_elementwise_fma(sp(q2.w), s2, da2);
        na3 = __builtin_elementwise_fma(sp(q3.z), s3, na3);
        da3 = __builtin_elementwise_fma(sp(q3.w), s3, da3);
    }

    combN[wu][0][lane] = na0; combD[wu][0][lane] = da0;
    combN[wu][1][lane] = na1; combD[wu][1][lane] = da1;
    combN[wu][2][lane] = na2; combD[wu][2][lane] = da2;
    combN[wu][3][lane] = na3; combD[wu][3][lane] = da3;
    __syncthreads();

    if (wu < 4) {                                // wave wu finishes h = ht4*4+wu
        v2f na = sp(0.f), da = sp(0.f);
        #pragma unroll
        for (int js = 0; js < 8; ++js) {
            na += combN[js][wu][lane];
            da += combD[js][wu][lane];
        }
        const int h = ht4 * 4 + wu;
        const size_t rowb = (size_t)h * LTC_B + b0;      // H x B row base
        if constexpr (MODE == 0) {
            ((v2f*)(o0 + rowb))[lane] = na;              // snumT (coalesced 8B)
            ((v2f*)(o1 + rowb))[lane] = da;              // sdenT
        } else {
            const float gl = gleak[h], vl = vleak[h], c0 = cm[h];
            const v2f vpre = ((const v2f*)(vT + rowb))[lane];   // K==H here
            const v2f num = __builtin_elementwise_fma(sp(c0), vpre, sp(gl * vl))
                          + na + ((const v2f*)(snumT + rowb))[lane];
            const v2f den = sp(c0 + gl) + da + ((const v2f*)(sdenT + rowb))[lane];
            const v2f vn = num * vrcp(den + sp(1e-8f));
            if constexpr (MODE == 1) {
                ((v2f*)(o0 + rowb))[lane] = vn;          // next vT (KxB)
            } else {
                const int b = b0 + 2 * lane;
                o0[(size_t)b * LTC_H + h]       = vn.x;  // final B x H
                o0[(size_t)(b + 1) * LTC_H + h] = vn.y;
            }
        }
    }
}

extern "C" void kernel_launch(void* const* d_in, const int* in_sizes, int n_in,
                              void* d_out, int out_size, void* d_ws, size_t ws_size,
                              hipStream_t stream) {
    const float* inputs = (const float*)d_in[0];   // B x I
    const float* state  = (const float*)d_in[1];   // B x H
    const float* smu    = (const float*)d_in[2];   // I x H
    const float* ssig   = (const float*)d_in[3];
    const float* sW     = (const float*)d_in[4];
    const float* serev  = (const float*)d_in[5];
    const float* mu     = (const float*)d_in[6];   // H x H
    const float* sig    = (const float*)d_in[7];
    const float* W      = (const float*)d_in[8];
    const float* erev   = (const float*)d_in[9];
    const float* vleak  = (const float*)d_in[10];  // H
    const float* gleak  = (const float*)d_in[11];
    const float* cm     = (const float*)d_in[12];

    float* out = (float*)d_out;                    // B x H
    char*  ws  = (char*)d_ws;
    float*  snumT = (float*)(ws);                            // 1MB  H x B
    float*  sdenT = (float*)(ws + 1 * 1048576);              // 1MB  H x B
    float*  vTA   = (float*)(ws + 2 * 1048576);              // 1MB  H x B
    float*  vTB   = (float*)(ws + 3 * 1048576);              // 1MB  H x B
    float4* rslab = (float4*)(ws + 4 * 1048576);             // 4MB  [128][512][4]
    float4* sslab = (float4*)(ws + 8 * 1048576);             // 2MB  [128][256][4]
    float*  inpT  = (float*)(ws + 10 * 1048576);             // 0.5MB I x B

    // Weight transform (f32 quads, once per launch). One thread per (j,h).
    ltc_prep<LTC_H, 9><<<LTC_H * LTC_H / 256, 256, 0, stream>>>(mu, sig, W, erev, rslab);
    ltc_prep<LTC_I, 8><<<LTC_I * LTC_H / 256, 256, 0, stream>>>(smu, ssig, sW, serev, sslab);

    // Transpose activations into K x B layout.
    ltc_transpose<<<dim3(LTC_I / 64, LTC_B / 64), 256, 0, stream>>>(inputs, inpT, LTC_B, LTC_I);
    ltc_transpose<<<dim3(LTC_H / 64, LTC_B / 64), 256, 0, stream>>>(state, vTA, LTC_B, LTC_H);

    dim3 grid(LTC_H / 4, LTC_B / 128);             // (128 h-tiles, 4 b-cols)
    dim3 blk(512);

    // Sensory pass -> snumT/sdenT (H x B).
    ltc_pass<LTC_I, 0><<<grid, blk, 0, stream>>>(
        inpT, sslab, nullptr, nullptr, nullptr, nullptr, nullptr,
        snumT, sdenT);

    // 6 unfolds: vTA -> vTB -> ... ; last writes B x H into d_out.
    const float* vin = vTA;
    float* vping[5] = {vTB, vTA, vTB, vTA, vTB};
    for (int s = 0; s < 5; ++s) {
        ltc_pass<LTC_H, 1><<<grid, blk, 0, stream>>>(
            vin, rslab, snumT, sdenT, vleak, gleak, cm,
            vping[s], nullptr);
        vin = vping[s];
    }
    ltc_pass<LTC_H, 2><<<grid, blk, 0, stream>>>(
        vin, rslab, snumT, sdenT, vleak, gleak, cm, out, nullptr);
}

// Round 14
// 287.675 us; speedup vs baseline: 1.0629x; 1.0119x over previous
//
#include <hip/hip_runtime.h>

#define LTC_B 512
#define LTC_H 512
#define LTC_I 256

typedef float v2f __attribute__((ext_vector_type(2)));
static constexpr float kL2E = 1.4426950408889634f;  // log2(e)

__device__ __forceinline__ v2f sp(float s) { return (v2f){s, s}; }
__device__ __forceinline__ v2f vexp2(v2f t) {
    return (v2f){__builtin_amdgcn_exp2f(t.x), __builtin_amdgcn_exp2f(t.y)};
}
__device__ __forceinline__ v2f vrcp(v2f t) {
    return (v2f){__builtin_amdgcn_rcpf(t.x), __builtin_amdgcn_rcpf(t.y)};
}

// f32 weight quad per (j,h): a = -sigma*log2(e), ec = 2^(mu*sigma*log2(e)),
// wz = W*erev, wd = W.  sigma(b,j,h) = 1 / (1 + ec * 2^(a*v(b,j))).
// Quad index = (ht4*K + j)*4 + hh4, h = ht4*4 + hh4: the 4 h's of one (ht4,j)
// are one contiguous 64B group -> batched s_load on the scalar pipe.
template<int K, int LOG2K>
__global__ void ltc_prep(const float* __restrict__ mu, const float* __restrict__ sigma,
                         const float* __restrict__ W, const float* __restrict__ erev,
                         float4* __restrict__ slab) {
    const int t = blockIdx.x * 256 + threadIdx.x;   // one thread per quad
    if (t >= K * LTC_H) return;
    const int hh4  = t & 3;
    const int rest = t >> 2;
    const int j    = rest & (K - 1);
    const int ht4  = rest >> LOG2K;
    const int h    = ht4 * 4 + hh4;
    const int g    = j * LTC_H + h;
    const float sg = sigma[g];
    float4 o;
    o.x = -sg * kL2E;                    // a
    o.y = exp2f(mu[g] * sg * kL2E);      // ec = 2^c
    o.z = W[g] * erev[g];                // wz
    o.w = W[g];                          // wd
    slab[t] = o;                         // coalesced 16B/lane
}

// 64x64 LDS tile transpose: in R x C row-major -> out C x R. grid (C/64, R/64).
__global__ void ltc_transpose(const float* __restrict__ in, float* __restrict__ out,
                              int R, int C) {
    __shared__ float tile[64][65];
    const int bx = blockIdx.x * 64;      // col base
    const int by = blockIdx.y * 64;      // row base
    const int tx = threadIdx.x & 63;
    const int t4 = threadIdx.x >> 6;
    #pragma unroll
    for (int r = t4; r < 64; r += 4)
        tile[r][tx] = in[(size_t)(by + r) * C + bx + tx];
    __syncthreads();
    #pragma unroll
    for (int r = t4; r < 64; r += 4)
        out[(size_t)(bx + r) * R + by + tx] = tile[tx][r];
}

// Lane = BATCH-PAIR (R13, 291.1us) with ONE isolated change: 4-way rcp
// batching per b-component -- ONE vrcp of the 4-h denominator product
// instead of two. Trans lane-ops per 8 evals: 12 -> 10 (8 exp2 + 2 rcp).
// The unwind muls are PACKED (pk_mul) and the two b-component chains are
// independent, unlike R12's scalar version whose serial chain regressed.
// This is the decisive test of the trans-throughput-wall hypothesis.
// Block = 512 thr = 8 waves = 8 j-slices for one (4-h tile, 128-b column).
// MODE: 0 = sensory (write snumT/sdenT HxB), 1 = recurrent (write vT KxB),
//       2 = last recurrent (write out B x H).
template<int K, int MODE>
__global__ __launch_bounds__(512, 8)
void ltc_pass(const float* __restrict__ vT,      // K x B (transposed)
              const float4* __restrict__ slab,   // [128][K][4]
              const float* __restrict__ snumT, const float* __restrict__ sdenT, // H x B
              const float* __restrict__ vleak, const float* __restrict__ gleak,
              const float* __restrict__ cm,
              float* __restrict__ o0, float* __restrict__ o1)
{
    constexpr int JW = K / 8;                    // j's per wave (64 / 32)

    __shared__ v2f combN[8][4][64];              // 16 KB na partials (b-pair)
    __shared__ v2f combD[8][4][64];              // 16 KB da partials

    const int tid  = threadIdx.x;
    const int lane = tid & 63;
    const int wu   = __builtin_amdgcn_readfirstlane(tid >> 6);  // j-slice
    const int ht4  = blockIdx.x;                 // 0..127
    const int b0   = blockIdx.y * 128;           // 128 b per block

    // wave's weight slice (wave-uniform float4 -> batched s_load)
    const float4* __restrict__ wq = slab + ((size_t)ht4 * K + (size_t)wu * JW) * 4;
    // per-lane v: coalesced 8B loads (b-pair), one per j
    const v2f* __restrict__ vp =
        (const v2f*)vT + (size_t)(wu * JW) * (LTC_B / 2) + (b0 >> 1) + lane;

    v2f na0 = sp(0.f), da0 = sp(0.f), na1 = sp(0.f), da1 = sp(0.f);
    v2f na2 = sp(0.f), da2 = sp(0.f), na3 = sp(0.f), da3 = sp(0.f);

    #pragma unroll 4
    for (int jj = 0; jj < JW; ++jj) {
        const v2f vj = vp[(size_t)jj * (LTC_B / 2)];
        const float4 q0 = wq[jj * 4 + 0];        // wave-uniform -> s_load
        const float4 q1 = wq[jj * 4 + 1];
        const float4 q2 = wq[jj * 4 + 2];
        const float4 q3 = wq[jj * 4 + 3];
        const v2f e0 = vexp2(sp(q0.x) * vj);
        const v2f e1 = vexp2(sp(q1.x) * vj);
        const v2f e2 = vexp2(sp(q2.x) * vj);
        const v2f e3 = vexp2(sp(q3.x) * vj);
        const v2f d0 = __builtin_elementwise_fma(sp(q0.y), e0, sp(1.0f));
        const v2f d1 = __builtin_elementwise_fma(sp(q1.y), e1, sp(1.0f));
        const v2f d2 = __builtin_elementwise_fma(sp(q2.y), e2, sp(1.0f));
        const v2f d3 = __builtin_elementwise_fma(sp(q3.y), e3, sp(1.0f));
        const v2f p01 = d0 * d1, p23 = d2 * d3;  // packed muls
        const v2f R = vrcp(p01 * p23);           // 1 rcp / 4 sigmoids (per b)
        const v2f r01 = R * p23, r23 = R * p01;
        const v2f s0 = r01 * d1, s1 = r01 * d0;
        const v2f s2 = r23 * d3, s3 = r23 * d2;
        na0 = __builtin_elementwise_fma(sp(q0.z), s0, na0);
        da0 = __builtin_elementwise_fma(sp(q0.w), s0, da0);
        na1 = __builtin_elementwise_fma(sp(q1.z), s1, na1);
        da1 = __builtin_elementwise_fma(sp(q1.w), s1, da1);
        na2 = __builtin_elementwise_fma(sp(q2.z), s2, na2);
        da2 = __builtin_elementwise_fma(sp(q2.w), s2, da2);
        na3 = __builtin_elementwise_fma(sp(q3.z), s3, na3);
        da3 = __builtin_elementwise_fma(sp(q3.w), s3, da3);
    }

    combN[wu][0][lane] = na0; combD[wu][0][lane] = da0;
    combN[wu][1][lane] = na1; combD[wu][1][lane] = da1;
    combN[wu][2][lane] = na2; combD[wu][2][lane] = da2;
    combN[wu][3][lane] = na3; combD[wu][3][lane] = da3;
    __syncthreads();

    if (wu < 4) {                                // wave wu finishes h = ht4*4+wu
        v2f na = sp(0.f), da = sp(0.f);
        #pragma unroll
        for (int js = 0; js < 8; ++js) {
            na += combN[js][wu][lane];
            da += combD[js][wu][lane];
        }
        const int h = ht4 * 4 + wu;
        const size_t rowb = (size_t)h * LTC_B + b0;      // H x B row base
        if constexpr (MODE == 0) {
            ((v2f*)(o0 + rowb))[lane] = na;              // snumT (coalesced 8B)
            ((v2f*)(o1 + rowb))[lane] = da;              // sdenT
        } else {
            const float gl = gleak[h], vl = vleak[h], c0 = cm[h];
            const v2f vpre = ((const v2f*)(vT + rowb))[lane];   // K==H here
            const v2f num = __builtin_elementwise_fma(sp(c0), vpre, sp(gl * vl))
                          + na + ((const v2f*)(snumT + rowb))[lane];
            const v2f den = sp(c0 + gl) + da + ((const v2f*)(sdenT + rowb))[lane];
            const v2f vn = num * vrcp(den + sp(1e-8f));
            if constexpr (MODE == 1) {
                ((v2f*)(o0 + rowb))[lane] = vn;          // next vT (KxB)
            } else {
                const int b = b0 + 2 * lane;
                o0[(size_t)b * LTC_H + h]       = vn.x;  // final B x H
                o0[(size_t)(b + 1) * LTC_H + h] = vn.y;
            }
        }
    }
}

extern "C" void kernel_launch(void* const* d_in, const int* in_sizes, int n_in,
                              void* d_out, int out_size, void* d_ws, size_t ws_size,
                              hipStream_t stream) {
    const float* inputs = (const float*)d_in[0];   // B x I
    const float* state  = (const float*)d_in[1];   // B x H
    const float* smu    = (const float*)d_in[2];   // I x H
    const float* ssig   = (const float*)d_in[3];
    const float* sW     = (const float*)d_in[4];
    const float* serev  = (const float*)d_in[5];
    const float* mu     = (const float*)d_in[6];   // H x H
    const float* sig    = (const float*)d_in[7];
    const float* W      = (const float*)d_in[8];
    const float* erev   = (const float*)d_in[9];
    const float* vleak  = (const float*)d_in[10];  // H
    const float* gleak  = (const float*)d_in[11];
    const float* cm     = (const float*)d_in[12];

    float* out = (float*)d_out;                    // B x H
    char*  ws  = (char*)d_ws;
    float*  snumT = (float*)(ws);                            // 1MB  H x B
    float*  sdenT = (float*)(ws + 1 * 1048576);              // 1MB  H x B
    float*  vTA   = (float*)(ws + 2 * 1048576);              // 1MB  H x B
    float*  vTB   = (float*)(ws + 3 * 1048576);              // 1MB  H x B
    float4* rslab = (float4*)(ws + 4 * 1048576);             // 4MB  [128][512][4]
    float4* sslab = (float4*)(ws + 8 * 1048576);             // 2MB  [128][256][4]
    float*  inpT  = (float*)(ws + 10 * 1048576);             // 0.5MB I x B

    // Weight transform (f32 quads, once per launch). One thread per (j,h).
    ltc_prep<LTC_H, 9><<<LTC_H * LTC_H / 256, 256, 0, stream>>>(mu, sig, W, erev, rslab);
    ltc_prep<LTC_I, 8><<<LTC_I * LTC_H / 256, 256, 0, stream>>>(smu, ssig, sW, serev, sslab);

    // Transpose activations into K x B layout.
    ltc_transpose<<<dim3(LTC_I / 64, LTC_B / 64), 256, 0, stream>>>(inputs, inpT, LTC_B, LTC_I);
    ltc_transpose<<<dim3(LTC_H / 64, LTC_B / 64), 256, 0, stream>>>(state, vTA, LTC_B, LTC_H);

    dim3 grid(LTC_H / 4, LTC_B / 128);             // (128 h-tiles, 4 b-cols)
    dim3 blk(512);

    // Sensory pass -> snumT/sdenT (H x B).
    ltc_pass<LTC_I, 0><<<grid, blk, 0, stream>>>(
        inpT, sslab, nullptr, nullptr, nullptr, nullptr, nullptr,
        snumT, sdenT);

    // 6 unfolds: vTA -> vTB -> ... ; last writes B x H into d_out.
    const float* vin = vTA;
    float* vping[5] = {vTB, vTA, vTB, vTA, vTB};
    for (int s = 0; s < 5; ++s) {
        ltc_pass<LTC_H, 1><<<grid, blk, 0, stream>>>(
            vin, rslab, snumT, sdenT, vleak, gleak, cm,
            vping[s], nullptr);
        vin = vping[s];
    }
    ltc_pass<LTC_H, 2><<<grid, blk, 0, stream>>>(
        vin, rslab, snumT, sdenT, vleak, gleak, cm, out, nullptr);
}